// Round 2
// baseline (253.801 us; speedup 1.0000x reference)
//
#include <hip/hip_runtime.h>

// Attention over channel dim: B=16, HW=16384, C=64, fp32.
// scores[b,q,k] = sum_hw Q[b,hw,q]*K[b,hw,k]; attn=softmax_k; out[b,hw,q]=sum_k attn[b,q,k]*V[b,hw,k]
//
// ws layout: partial scores [B][SPLIT][64][64] fp32, then attn_t [B][64k][64q] fp32 (256 KB).
// SPLIT=64 (16 MiB partial) if ws allows, else 32 (8 MiB).

#define TILE_ROWS 32                 // rows staged in LDS per iteration

// ---------------- Kernel A: partial scores (split-K GEMM, 8x8 register tile, double-buffered) ----------------
// All 4 waves compute the SAME 64x64 (q,k) tile over DISJOINT row subsets
// (r = i*4 + w). T14-style staging: issue next tile's global loads, compute
// current tile, then LDS-write the prefetched data; ONE barrier per iter.
// SPLIT=64 -> grid 1024 -> 4 blocks/CU (vs 2 at SPLIT=32): latency hiding
// against the shared per-CU LDS pipe (the dominant pipe load here).
template <int SPLIT>
__global__ __launch_bounds__(256) void scores_kernel(
    const float* __restrict__ Q, const float* __restrict__ K,
    float* __restrict__ partial) {
  constexpr int CH = 16384 / SPLIT;       // rows per split block
  constexpr int NT = CH / TILE_ROWS;      // tile iterations
  const int bs = blockIdx.x;              // b * SPLIT + s
  const int b = bs / SPLIT;
  const int s = bs % SPLIT;
  const int tid = threadIdx.x;
  const int w = tid >> 6;                 // wave id 0..3
  const int l = tid & 63;                 // lane
  const int q0 = (l >> 3) * 8;            // 8 q per lane
  const int k0 = (l & 7) * 8;             // 8 k per lane

  __shared__ union {
    struct { float4 q[2][512]; float4 k[2][512]; } t;  // 32 KB double-buffered tiles
    float red[2][4096];                                // 32 KB cross-wave reduction
  } lds;

  float acc[8][8];
#pragma unroll
  for (int i = 0; i < 8; ++i)
#pragma unroll
    for (int j = 0; j < 8; ++j) acc[i][j] = 0.f;

  const float4* Qg = (const float4*)(Q + ((size_t)b * 16384 + (size_t)s * CH) * 64);
  const float4* Kg = (const float4*)(K + ((size_t)b * 16384 + (size_t)s * CH) * 64);

  // prologue: stage tile 0 into buffer 0
  lds.t.q[0][tid]       = Qg[tid];
  lds.t.q[0][tid + 256] = Qg[tid + 256];
  lds.t.k[0][tid]       = Kg[tid];
  lds.t.k[0][tid + 256] = Kg[tid + 256];

  for (int t = 0; t < NT; ++t) {
    __syncthreads();                    // buf (t&1) ready; buf ((t+1)&1) free
    const int cb = t & 1;

    // issue next tile's global loads (latency hides under this tile's compute)
    float4 pq0, pq1, pk0, pk1;
    if (t + 1 < NT) {
      pq0 = Qg[(t + 1) * 512 + tid];
      pq1 = Qg[(t + 1) * 512 + tid + 256];
      pk0 = Kg[(t + 1) * 512 + tid];
      pk1 = Kg[(t + 1) * 512 + tid + 256];
    }

#pragma unroll
    for (int i = 0; i < 8; ++i) {
      const int r = (i << 2) + w;       // wave w handles rows w,4+w,...,28+w
      float4 qa = lds.t.q[cb][r * 16 + (q0 >> 2)];
      float4 qb = lds.t.q[cb][r * 16 + (q0 >> 2) + 1];
      float4 ka = lds.t.k[cb][r * 16 + (k0 >> 2)];
      float4 kb = lds.t.k[cb][r * 16 + (k0 >> 2) + 1];
      float qv[8] = {qa.x, qa.y, qa.z, qa.w, qb.x, qb.y, qb.z, qb.w};
      float kv[8] = {ka.x, ka.y, ka.z, ka.w, kb.x, kb.y, kb.z, kb.w};
#pragma unroll
      for (int ii = 0; ii < 8; ++ii)
#pragma unroll
        for (int jj = 0; jj < 8; ++jj)
          acc[ii][jj] += qv[ii] * kv[jj];
    }

    // write the prefetched tile into the other buffer (completes before next barrier)
    if (t + 1 < NT) {
      const int nb = (t + 1) & 1;
      lds.t.q[nb][tid]       = pq0;
      lds.t.q[nb][tid + 256] = pq1;
      lds.t.k[nb][tid]       = pk0;
      lds.t.k[nb][tid + 256] = pk1;
    }
  }

  // ---- cross-wave reduction: waves 2,3 publish; waves 0,1 add; halves summed on store ----
  __syncthreads();                      // all waves done reading tile LDS
  if (w >= 2) {
    float4* dst = (float4*)lds.red[w - 2];
#pragma unroll
    for (int i = 0; i < 8; ++i) {
      dst[(q0 + i) * 16 + (k0 >> 2)]     = make_float4(acc[i][0], acc[i][1], acc[i][2], acc[i][3]);
      dst[(q0 + i) * 16 + (k0 >> 2) + 1] = make_float4(acc[i][4], acc[i][5], acc[i][6], acc[i][7]);
    }
  }
  __syncthreads();
  if (w < 2) {
    float4* dst = (float4*)lds.red[w];
#pragma unroll
    for (int i = 0; i < 8; ++i) {
      float4 u = dst[(q0 + i) * 16 + (k0 >> 2)];
      float4 v = dst[(q0 + i) * 16 + (k0 >> 2) + 1];
      dst[(q0 + i) * 16 + (k0 >> 2)]     = make_float4(u.x + acc[i][0], u.y + acc[i][1], u.z + acc[i][2], u.w + acc[i][3]);
      dst[(q0 + i) * 16 + (k0 >> 2) + 1] = make_float4(v.x + acc[i][4], v.y + acc[i][5], v.z + acc[i][6], v.w + acc[i][7]);
    }
  }
  __syncthreads();
  // cooperative coalesced store of the reduced 64x64 tile
  float4* p4 = (float4*)(partial + (size_t)bs * 4096);
  const float4* r0 = (const float4*)lds.red[0];
  const float4* r1 = (const float4*)lds.red[1];
#pragma unroll
  for (int c = 0; c < 4; ++c) {
    float4 x = r0[c * 256 + tid];
    float4 y = r1[c * 256 + tid];
    p4[c * 256 + tid] = make_float4(x.x + y.x, x.y + y.y, x.z + y.z, x.w + y.w);
  }
}

// ---------------- Kernel B: reduce partials + softmax over k, store TRANSPOSED attn_t[b][k][q] ----------------
template <int SPLIT>
__global__ __launch_bounds__(64) void softmax_kernel(
    const float* __restrict__ partial, float* __restrict__ attn_t) {
  const int blk = blockIdx.x;           // b*16 + qquad
  const int b = blk >> 4;
  const int q0 = (blk & 15) * 4;
  const int lane = threadIdx.x;
  const int ql = lane >> 4;             // 0..3  (q = q0+ql)
  const int k4 = lane & 15;             // float4 column

  const float4* P = (const float4*)partial;
  float4 v = make_float4(0.f, 0.f, 0.f, 0.f);
  for (int s = 0; s < SPLIT; ++s) {
    float4 t = P[((size_t)(b * SPLIT + s) * 64 + q0 + ql) * 16 + k4];
    v.x += t.x; v.y += t.y; v.z += t.z; v.w += t.w;
  }

  float m = fmaxf(fmaxf(v.x, v.y), fmaxf(v.z, v.w));
#pragma unroll
  for (int off = 8; off > 0; off >>= 1)
    m = fmaxf(m, __shfl_xor(m, off, 64));   // reduce across the 16 lanes sharing q
  float4 e = make_float4(__expf(v.x - m), __expf(v.y - m), __expf(v.z - m), __expf(v.w - m));
  float sum = e.x + e.y + e.z + e.w;
#pragma unroll
  for (int off = 8; off > 0; off >>= 1)
    sum += __shfl_xor(sum, off, 64);
  const float inv = 1.f / sum;

  float* A = attn_t + (size_t)b * 4096;     // [k][q] layout
  A[(4 * k4 + 0) * 64 + q0 + ql] = e.x * inv;
  A[(4 * k4 + 1) * 64 + q0 + ql] = e.y * inv;
  A[(4 * k4 + 2) * 64 + q0 + ql] = e.z * inv;
  A[(4 * k4 + 3) * 64 + q0 + ql] = e.w * inv;
}

// ---------------- Kernel C: out = V * attn_t, lane = output row, attn via SCALAR pipe ----------------
// Each lane computes out[row][0..63] (64 accumulators). V[row][*] is read as
// 16 x b128 global loads (per-lane own row; the 4 k4-iters sharing each 64B
// line are consecutive -> L1 merges, HBM traffic exact). attn_t[k][q] is
// wave-uniform (index depends only on blockIdx + loop constants) -> compiler
// emits s_load + v_fmac_f32 v,s,v. ZERO LDS traffic; scalar A is L2-resident
// (256 KB total). 1-wave blocks, no barriers; ~80 VGPR -> ~6 waves/SIMD.
__global__ __launch_bounds__(64) void out_kernel(
    const float* __restrict__ V, const float* __restrict__ attn_t,
    float* __restrict__ out) {
  const int blk = blockIdx.x;           // b*256 + tile (256 tiles of 64 rows)
  const int b = blk >> 8;
  const int tile = blk & 255;
  const int row = tile * 64 + (int)threadIdx.x;

  const float4* V4 = (const float4*)(V + ((size_t)b * 16384 + row) * 64);
  const float* A = attn_t + (size_t)b * 4096;   // [k][q], contiguous in q

  float acc[64];
#pragma unroll
  for (int q = 0; q < 64; ++q) acc[q] = 0.f;

  float4 vv = V4[0];
  for (int k4 = 0; k4 < 16; ++k4) {
    float4 vn = vv;
    if (k4 < 15) vn = V4[k4 + 1];       // prefetch next V quad under this iter's FMAs
    const float* A0 = A + (size_t)(4 * k4) * 64;
#pragma unroll
    for (int q = 0; q < 64; ++q) {
      acc[q] += vv.x * A0[q] + vv.y * A0[64 + q] + vv.z * A0[128 + q] + vv.w * A0[192 + q];
    }
    vv = vn;
  }

  float4* og = (float4*)(out + ((size_t)b * 16384 + row) * 64);
#pragma unroll
  for (int q4 = 0; q4 < 16; ++q4)
    og[q4] = make_float4(acc[4 * q4], acc[4 * q4 + 1], acc[4 * q4 + 2], acc[4 * q4 + 3]);
}

extern "C" void kernel_launch(void* const* d_in, const int* in_sizes, int n_in,
                              void* d_out, int out_size, void* d_ws, size_t ws_size,
                              hipStream_t stream) {
  const float* Q = (const float*)d_in[0];
  const float* K = (const float*)d_in[1];
  const float* V = (const float*)d_in[2];
  float* out = (float*)d_out;

  const size_t need64 = (size_t)16 * 64 * 4096 * 4 + (size_t)16 * 4096 * 4;  // 16 MiB + 256 KiB

  if (ws_size >= need64) {
    float* partial = (float*)d_ws;                           // 16*64*4096 floats = 16 MiB
    float* attn_t = partial + (size_t)16 * 64 * 4096;        // 256 KB, [b][k][q]
    scores_kernel<64><<<16 * 64, 256, 0, stream>>>(Q, K, partial);
    softmax_kernel<64><<<16 * 16, 64, 0, stream>>>(partial, attn_t);
    out_kernel<<<16 * 256, 64, 0, stream>>>(V, attn_t, out);
  } else {
    float* partial = (float*)d_ws;                           // 8 MiB
    float* attn_t = partial + (size_t)16 * 32 * 4096;
    scores_kernel<32><<<16 * 32, 256, 0, stream>>>(Q, K, partial);
    softmax_kernel<32><<<16 * 16, 64, 0, stream>>>(partial, attn_t);
    out_kernel<<<16 * 256, 64, 0, stream>>>(V, attn_t, out);
  }
}